// Round 1
// baseline (275.928 us; speedup 1.0000x reference)
//
#include <hip/hip_runtime.h>
#include <hip/hip_bf16.h>

typedef __attribute__((ext_vector_type(8))) short short8;       // 8 x bf16 (4 VGPR)
typedef __attribute__((ext_vector_type(4))) float f32x4;        // MFMA acc
typedef __attribute__((ext_vector_type(4))) unsigned short ushort4v;

__device__ __forceinline__ unsigned short f2bf(float f) {
    __hip_bfloat16 h = __float2bfloat16(f);
    return __builtin_bit_cast(unsigned short, h);
}

// ---------------- K0: w_qk fp32 -> bf16 ----------------
__global__ __launch_bounds__(256) void k0_cvt(const float* __restrict__ src,
                                              unsigned short* __restrict__ dst, int n) {
    int i = blockIdx.x * 256 + threadIdx.x;
    if (i < n) dst[i] = f2bf(src[i]);
}

// ---------------- K1: Q-GEMM + normalize ----------------
// grid: 128 windows * 16 token-blocks. block = 256 thr (4 waves).
// D[c][t] = sum_n W[c][n] * Xw[n][t];  M=c(256, 4 waves x 64), N=t(64), K=512.
// Output: qn[win][t][c] bf16, normalized per token.
__global__ __launch_bounds__(256) void k1_qgemm(const float* __restrict__ x,
                                                const unsigned short* __restrict__ wbf,
                                                unsigned short* __restrict__ qn) {
    const int blk = blockIdx.x;
    const int win = blk >> 4;
    const int t0  = (blk & 15) << 6;
    const int b   = win >> 2;
    const int h0  = ((win >> 1) & 1) << 5;
    const int w0  = (win & 1) << 5;

    __shared__ __align__(16) unsigned short lA[256][40];  // W tile [c][k], pad->80B rows
    __shared__ __align__(16) unsigned short lB[64][40];   // X tile [t][k]
    __shared__ float nbuf[4][64];

    const int tid  = threadIdx.x;
    const int lane = tid & 63;
    const int wv   = tid >> 6;
    const int lo   = lane & 15;
    const int hi   = lane >> 4;

    f32x4 acc[4][4];
#pragma unroll
    for (int mi = 0; mi < 4; ++mi)
#pragma unroll
        for (int ni = 0; ni < 4; ++ni) acc[mi][ni] = (f32x4){0.f, 0.f, 0.f, 0.f};

    // x[b][n][h0 + t0/32 + t/32][w0 + t%32]
    const float* xblk = x + (size_t)b * 512 * 4096 + (size_t)(h0 + (t0 >> 5)) * 64 + w0;
    const int bt = lane;  // token 0..63 staged by this thread (n-slab = wv*8)

    for (int kt = 0; kt < 16; ++kt) {
        const int k0 = kt << 5;
        // stage A: 256x32 bf16 (16B vector copies)
#pragma unroll
        for (int r = 0; r < 4; ++r) {
            int cid = r * 256 + tid;        // 0..1023
            int c   = cid >> 2;
            int n8  = cid & 3;
            *(short8*)&lA[c][n8 * 8] = *(const short8*)(wbf + c * 512 + k0 + n8 * 8);
        }
        // stage B: 64x32 fp32->bf16
        {
            const float* xp = xblk + (size_t)(k0 + wv * 8) * 4096 + ((bt >> 5) * 64 + (bt & 31));
            unsigned short tmp[8];
#pragma unroll
            for (int m = 0; m < 8; ++m) tmp[m] = f2bf(xp[(size_t)m * 4096]);
            ushort4v v0 = {tmp[0], tmp[1], tmp[2], tmp[3]};
            ushort4v v1 = {tmp[4], tmp[5], tmp[6], tmp[7]};
            *(ushort4v*)&lB[bt][wv * 8]     = v0;
            *(ushort4v*)&lB[bt][wv * 8 + 4] = v1;
        }
        __syncthreads();

        short8 af[4], bfr[4];
#pragma unroll
        for (int mi = 0; mi < 4; ++mi)
            af[mi] = *(const short8*)&lA[wv * 64 + mi * 16 + lo][hi * 8];
#pragma unroll
        for (int ni = 0; ni < 4; ++ni)
            bfr[ni] = *(const short8*)&lB[ni * 16 + lo][hi * 8];
#pragma unroll
        for (int mi = 0; mi < 4; ++mi)
#pragma unroll
            for (int ni = 0; ni < 4; ++ni)
                acc[mi][ni] = __builtin_amdgcn_mfma_f32_16x16x32_bf16(af[mi], bfr[ni], acc[mi][ni], 0, 0, 0);
        __syncthreads();
    }

    // ---- per-token norm over c (within lane: mi,reg; across lanes: hi; across waves: LDS) ----
    float part[4];
#pragma unroll
    for (int ni = 0; ni < 4; ++ni) {
        float s = 0.f;
#pragma unroll
        for (int mi = 0; mi < 4; ++mi)
#pragma unroll
            for (int r = 0; r < 4; ++r) s += acc[mi][ni][r] * acc[mi][ni][r];
        s += __shfl_xor(s, 16);
        s += __shfl_xor(s, 32);
        part[ni] = s;
    }
    if (hi == 0) {
#pragma unroll
        for (int ni = 0; ni < 4; ++ni) nbuf[wv][ni * 16 + lo] = part[ni];
    }
    __syncthreads();

#pragma unroll
    for (int ni = 0; ni < 4; ++ni) {
        const int tl = ni * 16 + lo;
        float s = nbuf[0][tl] + nbuf[1][tl] + nbuf[2][tl] + nbuf[3][tl];
        float inv = 1.f / (sqrtf(s) + 1e-6f);
        size_t base = ((size_t)win * 1024 + (size_t)(t0 + tl)) * 256;
#pragma unroll
        for (int mi = 0; mi < 4; ++mi) {
            int c = wv * 64 + mi * 16 + hi * 4;
            ushort4v o = {f2bf(acc[mi][ni][0] * inv), f2bf(acc[mi][ni][1] * inv),
                          f2bf(acc[mi][ni][2] * inv), f2bf(acc[mi][ni][3] * inv)};
            *(ushort4v*)(qn + base + c) = o;
        }
    }
}

// ---------------- K2: S = Q Q^T, relu, PV (+rowsum via ones column) ----------------
// grid: 128 windows * 16 query-blocks (64 q each). block = 256 thr (4 waves).
__global__ __launch_bounds__(256) void k2_attn(const unsigned short* __restrict__ qn,
                                               const float* __restrict__ v,
                                               float* __restrict__ out) {
    const int blk = blockIdx.x;
    const int win = blk >> 4;
    const int q0  = (blk & 15) << 6;
    const int b   = win >> 2;
    const int h0  = ((win >> 1) & 1) << 5;
    const int w0  = (win & 1) << 5;

    __shared__ __align__(16) unsigned short lK[64][264];  // key chunk [key][c]
    __shared__ __align__(16) unsigned short lP[64][72];   // P bf16 [q][key]
    __shared__ __align__(16) unsigned short lV[16][72];   // V^T [ch][key], row15 = ones

    const int tid  = threadIdx.x;
    const int lane = tid & 63;
    const int wv   = tid >> 6;
    const int lo   = lane & 15;
    const int hi   = lane >> 4;
    const int wq   = wv >> 1, wk = wv & 1;

    const unsigned short* qwin = qn + (size_t)win * 1024 * 256;

    // loop-invariant A-frags (this wave's 32 query rows)
    short8 qa[2][8];
#pragma unroll
    for (int mi = 0; mi < 2; ++mi)
#pragma unroll
        for (int kc = 0; kc < 8; ++kc)
            qa[mi][kc] = *(const short8*)(qwin + (size_t)(q0 + wq * 32 + mi * 16 + lo) * 256 + kc * 32 + hi * 8);

    f32x4 accout = (f32x4){0.f, 0.f, 0.f, 0.f};
    const float* vbase = v + (size_t)b * 15 * 4096 + (size_t)h0 * 64 + w0;

    for (int chk = 0; chk < 16; ++chk) {
        const int kbase = chk << 6;
        // stage keys: 64x256 bf16
#pragma unroll
        for (int r = 0; r < 8; ++r) {
            int cid = r * 256 + tid;     // 0..2047
            int row = cid >> 5;
            int c8  = cid & 31;
            *(short8*)&lK[row][c8 * 8] = *(const short8*)(qwin + (size_t)(kbase + row) * 256 + c8 * 8);
        }
        // stage V^T 16x64 (ch 15 = ones)
        {
            int j  = tid & 63;
            int c4 = tid >> 6;
            int jk = kbase + j;
            const float* vp = vbase + (size_t)((jk >> 5) * 64 + (jk & 31));
#pragma unroll
            for (int cc = 0; cc < 4; ++cc) {
                int chn = c4 * 4 + cc;
                float val = (chn < 15) ? vp[(size_t)chn * 4096] : 1.0f;
                lV[chn][j] = f2bf(val);
            }
        }
        __syncthreads();

        // S-MFMA: 32q x 32k per wave, K=256
        f32x4 s[2][2];
#pragma unroll
        for (int mi = 0; mi < 2; ++mi)
#pragma unroll
            for (int ni = 0; ni < 2; ++ni) s[mi][ni] = (f32x4){0.f, 0.f, 0.f, 0.f};
#pragma unroll
        for (int kc = 0; kc < 8; ++kc) {
            short8 kb0 = *(const short8*)&lK[wk * 32 + lo][kc * 32 + hi * 8];
            short8 kb1 = *(const short8*)&lK[wk * 32 + 16 + lo][kc * 32 + hi * 8];
            s[0][0] = __builtin_amdgcn_mfma_f32_16x16x32_bf16(qa[0][kc], kb0, s[0][0], 0, 0, 0);
            s[0][1] = __builtin_amdgcn_mfma_f32_16x16x32_bf16(qa[0][kc], kb1, s[0][1], 0, 0, 0);
            s[1][0] = __builtin_amdgcn_mfma_f32_16x16x32_bf16(qa[1][kc], kb0, s[1][0], 0, 0, 0);
            s[1][1] = __builtin_amdgcn_mfma_f32_16x16x32_bf16(qa[1][kc], kb1, s[1][1], 0, 0, 0);
        }
        // relu -> bf16 -> lP
#pragma unroll
        for (int mi = 0; mi < 2; ++mi)
#pragma unroll
            for (int ni = 0; ni < 2; ++ni)
#pragma unroll
                for (int r = 0; r < 4; ++r)
                    lP[wq * 32 + mi * 16 + hi * 4 + r][wk * 32 + ni * 16 + lo] =
                        f2bf(fmaxf(s[mi][ni][r], 0.f));
        __syncthreads();

        // PV: each wave 16 q rows, N=16 (15 v-ch + rowsum), K=64
#pragma unroll
        for (int ks = 0; ks < 2; ++ks) {
            short8 pa  = *(const short8*)&lP[wv * 16 + lo][ks * 32 + hi * 8];
            short8 vbf = *(const short8*)&lV[lo][ks * 32 + hi * 8];
            accout = __builtin_amdgcn_mfma_f32_16x16x32_bf16(pa, vbf, accout, 0, 0, 0);
        }
        __syncthreads();
    }

    // epilogue: divide by rowsum (ch 15) and store
#pragma unroll
    for (int r = 0; r < 4; ++r) {
        float rs = __shfl(accout[r], (lane & 48) | 15);
        if (lo < 15) {
            int q = q0 + wv * 16 + hi * 4 + r;
            out[(size_t)(b * 15 + lo) * 4096 + (size_t)(h0 + (q >> 5)) * 64 + (w0 + (q & 31))] =
                accout[r] / (rs + 1e-6f);
        }
    }
}

extern "C" void kernel_launch(void* const* d_in, const int* in_sizes, int n_in,
                              void* d_out, int out_size, void* d_ws, size_t ws_size,
                              hipStream_t stream) {
    const float* x = (const float*)d_in[0];
    const float* v = (const float*)d_in[1];
    const float* w = (const float*)d_in[2];
    float* out = (float*)d_out;

    unsigned short* qn  = (unsigned short*)d_ws;                         // 128*1024*256 bf16 = 64 MiB
    unsigned short* wbf = (unsigned short*)((char*)d_ws + (size_t)128 * 1024 * 256 * 2);

    k0_cvt<<<512, 256, 0, stream>>>(w, wbf, 256 * 512);
    k1_qgemm<<<2048, 256, 0, stream>>>(x, wbf, qn);
    k2_attn<<<2048, 256, 0, stream>>>(qn, v, out);
}

// Round 2
// 218.571 us; speedup vs baseline: 1.2624x; 1.2624x over previous
//
#include <hip/hip_runtime.h>
#include <hip/hip_bf16.h>

typedef __attribute__((ext_vector_type(8))) short short8;       // 8 x bf16 (4 VGPR)
typedef __attribute__((ext_vector_type(4))) float f32x4;        // MFMA acc / float4
typedef __attribute__((ext_vector_type(4))) unsigned short ushort4v;

__device__ __forceinline__ unsigned short f2bf(float f) {
    __hip_bfloat16 h = __float2bfloat16(f);
    return __builtin_bit_cast(unsigned short, h);
}

// ---------------- K0: w_qk fp32 -> bf16 ----------------
__global__ __launch_bounds__(256) void k0_cvt(const float* __restrict__ src,
                                              unsigned short* __restrict__ dst, int n) {
    int i = blockIdx.x * 256 + threadIdx.x;
    if (i < n) dst[i] = f2bf(src[i]);
}

// ---------------- K1: Q-GEMM + normalize ----------------
// grid: 128 windows * 16 token-blocks. block = 256 thr (4 waves).
// D[c][t] = sum_n W[c][n] * Xw[n][t];  M=c(256, 4 waves x 64), N=t(64), K=512.
// Output: qn[win][t][c] bf16, normalized per token.
__global__ __launch_bounds__(256) void k1_qgemm(const float* __restrict__ x,
                                                const unsigned short* __restrict__ wbf,
                                                unsigned short* __restrict__ qn) {
    const int blk = blockIdx.x;
    const int win = blk >> 4;
    const int t0  = (blk & 15) << 6;
    const int b   = win >> 2;
    const int h0  = ((win >> 1) & 1) << 5;
    const int w0  = (win & 1) << 5;

    __shared__ __align__(16) unsigned short lA[256][40];  // W tile [c][k]
    __shared__ __align__(16) unsigned short lB[64][40];   // X tile [t][k]
    __shared__ float nbuf[4][64];

    const int tid  = threadIdx.x;
    const int lane = tid & 63;
    const int wv   = tid >> 6;
    const int lo   = lane & 15;
    const int hi   = lane >> 4;

    f32x4 acc[4][4];
#pragma unroll
    for (int mi = 0; mi < 4; ++mi)
#pragma unroll
        for (int ni = 0; ni < 4; ++ni) acc[mi][ni] = (f32x4){0.f, 0.f, 0.f, 0.f};

    const float* xblk = x + (size_t)b * 512 * 4096 + (size_t)(h0 + (t0 >> 5)) * 64 + w0;

    for (int kt = 0; kt < 16; ++kt) {
        const int k0 = kt << 5;
        // stage A: 256x32 bf16 (16B vector copies)
#pragma unroll
        for (int r = 0; r < 4; ++r) {
            int cid = r * 256 + tid;        // 0..1023
            int c   = cid >> 2;
            int n8  = cid & 3;
            *(short8*)&lA[c][n8 * 8] = *(const short8*)(wbf + c * 512 + k0 + n8 * 8);
        }
        // stage B: 32ch x 64tok, vectorized float4 x-loads
#pragma unroll
        for (int r = 0; r < 2; ++r) {
            int idx  = r * 256 + tid;       // 0..511
            int k    = idx >> 4;            // 0..31
            int f4   = idx & 15;
            int hrow = f4 >> 3;             // 0..1
            int wq   = f4 & 7;              // 0..7
            f32x4 d  = *(const f32x4*)(xblk + (size_t)(k0 + k) * 4096 + hrow * 64 + wq * 4);
            int t    = hrow * 32 + wq * 4;
            lB[t + 0][k] = f2bf(d[0]);
            lB[t + 1][k] = f2bf(d[1]);
            lB[t + 2][k] = f2bf(d[2]);
            lB[t + 3][k] = f2bf(d[3]);
        }
        __syncthreads();

        short8 af[4], bfr[4];
#pragma unroll
        for (int mi = 0; mi < 4; ++mi)
            af[mi] = *(const short8*)&lA[wv * 64 + mi * 16 + lo][hi * 8];
#pragma unroll
        for (int ni = 0; ni < 4; ++ni)
            bfr[ni] = *(const short8*)&lB[ni * 16 + lo][hi * 8];
#pragma unroll
        for (int mi = 0; mi < 4; ++mi)
#pragma unroll
            for (int ni = 0; ni < 4; ++ni)
                acc[mi][ni] = __builtin_amdgcn_mfma_f32_16x16x32_bf16(af[mi], bfr[ni], acc[mi][ni], 0, 0, 0);
        __syncthreads();
    }

    // ---- per-token norm over c ----
    float part[4];
#pragma unroll
    for (int ni = 0; ni < 4; ++ni) {
        float s = 0.f;
#pragma unroll
        for (int mi = 0; mi < 4; ++mi)
#pragma unroll
            for (int r = 0; r < 4; ++r) s += acc[mi][ni][r] * acc[mi][ni][r];
        s += __shfl_xor(s, 16);
        s += __shfl_xor(s, 32);
        part[ni] = s;
    }
    if (hi == 0) {
#pragma unroll
        for (int ni = 0; ni < 4; ++ni) nbuf[wv][ni * 16 + lo] = part[ni];
    }
    __syncthreads();

#pragma unroll
    for (int ni = 0; ni < 4; ++ni) {
        const int tl = ni * 16 + lo;
        float s = nbuf[0][tl] + nbuf[1][tl] + nbuf[2][tl] + nbuf[3][tl];
        float inv = 1.f / (sqrtf(s) + 1e-6f);
        size_t base = ((size_t)win * 1024 + (size_t)(t0 + tl)) * 256;
#pragma unroll
        for (int mi = 0; mi < 4; ++mi) {
            int c = wv * 64 + mi * 16 + hi * 4;
            ushort4v o = {f2bf(acc[mi][ni][0] * inv), f2bf(acc[mi][ni][1] * inv),
                          f2bf(acc[mi][ni][2] * inv), f2bf(acc[mi][ni][3] * inv)};
            *(ushort4v*)(qn + base + c) = o;
        }
    }
}

// ---------------- K2: S = Q Q^T, relu, PV (+rowsum via ones column) ----------------
// grid: 512 = 128 windows * 4 query-blocks (256 q each); bid&127 = window (XCD-swizzle:
// the 4 blocks of a window are 128 apart -> same bid%8 -> same XCD -> shared L2 keys).
// block = 256 thr (4 waves); wave owns 64 queries, qa[4][8] hoisted (128 VGPR).
__global__ __launch_bounds__(256, 2) void k2_attn(const unsigned short* __restrict__ qn,
                                                  const float* __restrict__ v,
                                                  float* __restrict__ out) {
    const int g   = blockIdx.x;
    const int win = g & 127;
    const int qb  = g >> 7;
    const int q0  = qb << 8;
    const int b   = win >> 2;
    const int h0  = ((win >> 1) & 1) << 5;
    const int w0  = (win & 1) << 5;

    __shared__ __align__(16) unsigned short lK[64 * 256];   // XOR-swizzled, 32 KB
    __shared__ __align__(16) unsigned short lP[256][72];    // 36 KB (wave-private rows)
    __shared__ __align__(16) unsigned short lV[16][72];     // row15 = ones

    const int tid  = threadIdx.x;
    const int lane = tid & 63;
    const int wv   = tid >> 6;
    const int lo   = lane & 15;
    const int hi   = lane >> 4;

    const unsigned short* qwin = qn + (size_t)win * 1024 * 256;
    const int qw0 = q0 + wv * 64;

    // hoisted A-frags (wave's 64 query rows x 256 ch)
    short8 qa[4][8];
#pragma unroll
    for (int mi = 0; mi < 4; ++mi)
#pragma unroll
        for (int kc = 0; kc < 8; ++kc)
            qa[mi][kc] = *(const short8*)(qwin + (size_t)(qw0 + mi * 16 + lo) * 256 + kc * 32 + hi * 8);

    f32x4 accout[4];
#pragma unroll
    for (int t = 0; t < 4; ++t) accout[t] = (f32x4){0.f, 0.f, 0.f, 0.f};

    const float* vbase = v + (size_t)b * 15 * 4096 + (size_t)h0 * 64 + w0;

    for (int chk = 0; chk < 16; ++chk) {
        const int kbase = chk << 6;
        __syncthreads();   // prev chunk's lK/lV reads done
        // stage keys: 64x256 bf16, XOR-swizzled ((row&7)<<4 on byte addr)
#pragma unroll
        for (int r = 0; r < 8; ++r) {
            int idx  = r * 256 + tid;    // 16B-unit index 0..2047
            int row  = idx >> 5;
            int slot = idx & 31;
            short8 d = *(const short8*)(qwin + (size_t)(kbase + row) * 256 + slot * 8);
            int off  = (row * 512 + slot * 16) ^ ((row & 7) << 4);
            *(short8*)((char*)lK + off) = d;
        }
        // stage V^T 16x64 (ch 15 = ones)
        {
            int j  = tid & 63;
            int c4 = tid >> 6;
            int jk = kbase + j;
            const float* vp = vbase + ((jk >> 5) * 64 + (jk & 31));
#pragma unroll
            for (int cc = 0; cc < 4; ++cc) {
                int chn = c4 * 4 + cc;
                float val = (chn < 15) ? vp[(size_t)chn * 4096] : 1.0f;
                lV[chn][j] = f2bf(val);
            }
        }
        __syncthreads();   // staging visible

        // S: 64q x 64k per wave; per ni: 1 kb read feeds 4 MFMA
#pragma unroll
        for (int ni = 0; ni < 4; ++ni) {
            f32x4 s[4];
#pragma unroll
            for (int mi = 0; mi < 4; ++mi) s[mi] = (f32x4){0.f, 0.f, 0.f, 0.f};
#pragma unroll
            for (int kc = 0; kc < 8; ++kc) {
                int row = ni * 16 + lo;
                int off = (row * 512 + kc * 64 + hi * 16) ^ ((row & 7) << 4);
                short8 kb = *(const short8*)((char*)lK + off);
#pragma unroll
                for (int mi = 0; mi < 4; ++mi)
                    s[mi] = __builtin_amdgcn_mfma_f32_16x16x32_bf16(qa[mi][kc], kb, s[mi], 0, 0, 0);
            }
            // relu -> bf16 -> lP (wave-private rows; no barrier needed before PV)
#pragma unroll
            for (int mi = 0; mi < 4; ++mi)
#pragma unroll
                for (int r = 0; r < 4; ++r)
                    lP[wv * 64 + mi * 16 + hi * 4 + r][ni * 16 + lo] = f2bf(fmaxf(s[mi][r], 0.f));
        }

        // PV: per wave 64q, N=16 (15 v-ch + rowsum), K=64
#pragma unroll
        for (int t = 0; t < 4; ++t) {
#pragma unroll
            for (int ks = 0; ks < 2; ++ks) {
                short8 pa  = *(const short8*)&lP[wv * 64 + t * 16 + lo][ks * 32 + hi * 8];
                short8 vbf = *(const short8*)&lV[lo][ks * 32 + hi * 8];
                accout[t] = __builtin_amdgcn_mfma_f32_16x16x32_bf16(pa, vbf, accout[t], 0, 0, 0);
            }
        }
    }

    // epilogue: divide by rowsum (ch 15) and store
#pragma unroll
    for (int t = 0; t < 4; ++t) {
#pragma unroll
        for (int r = 0; r < 4; ++r) {
            float rs = __shfl(accout[t][r], (lane & 48) | 15);
            if (lo < 15) {
                int q = qw0 + t * 16 + hi * 4 + r;
                out[(size_t)(b * 15 + lo) * 4096 + (size_t)(h0 + (q >> 5)) * 64 + (w0 + (q & 31))] =
                    accout[t][r] / (rs + 1e-6f);
            }
        }
    }
}

extern "C" void kernel_launch(void* const* d_in, const int* in_sizes, int n_in,
                              void* d_out, int out_size, void* d_ws, size_t ws_size,
                              hipStream_t stream) {
    const float* x = (const float*)d_in[0];
    const float* v = (const float*)d_in[1];
    const float* w = (const float*)d_in[2];
    float* out = (float*)d_out;

    unsigned short* qn  = (unsigned short*)d_ws;                         // 64 MiB
    unsigned short* wbf = (unsigned short*)((char*)d_ws + (size_t)128 * 1024 * 256 * 2);

    k0_cvt<<<512, 256, 0, stream>>>(w, wbf, 256 * 512);
    k1_qgemm<<<2048, 256, 0, stream>>>(x, wbf, qn);
    k2_attn<<<512, 256, 0, stream>>>(qn, v, out);
}

// Round 3
// 158.565 us; speedup vs baseline: 1.7402x; 1.3784x over previous
//
#include <hip/hip_runtime.h>
#include <hip/hip_bf16.h>

typedef __attribute__((ext_vector_type(8))) short short8;       // 8 x bf16 (4 VGPR)
typedef __attribute__((ext_vector_type(4))) float f32x4;        // MFMA acc / float4
typedef __attribute__((ext_vector_type(2))) float f32x2;
typedef __attribute__((ext_vector_type(4))) unsigned short ushort4v;
typedef __attribute__((ext_vector_type(2))) unsigned int uint32x2;

__device__ __forceinline__ unsigned short f2bf(float f) {
    __hip_bfloat16 h = __float2bfloat16(f);
    return __builtin_bit_cast(unsigned short, h);
}
__device__ __forceinline__ unsigned int pack2(float a, float b) {
    return (unsigned int)f2bf(a) | ((unsigned int)f2bf(b) << 16);
}
__device__ __forceinline__ void gload_lds16(const void* g, void* l) {
    __builtin_amdgcn_global_load_lds((const __attribute__((address_space(1))) unsigned int*)g,
                                     (__attribute__((address_space(3))) unsigned int*)l, 16, 0, 0);
}

// ---------------- K0: w_qk fp32 -> bf16 ----------------
__global__ __launch_bounds__(256) void k0_cvt(const float* __restrict__ src,
                                              unsigned short* __restrict__ dst, int n) {
    int i = blockIdx.x * 256 + threadIdx.x;
    if (i < n) dst[i] = f2bf(src[i]);
}

// ---------------- K1: Q-GEMM + normalize, writes SWIZZLED qn ----------------
// grid: 128 windows * 8 token-blocks (128 tok each). block = 256 thr (4 waves).
// D[c][t] = sum_n W[c][n] * Xw[n][t];  M=c(256, 4 waves x 64), N=t(128), K=512.
// qn storage: byte offset within window = (row*512 + 2c) ^ ((row&7)<<4).
__global__ __launch_bounds__(256, 2) void k1_qgemm(const float* __restrict__ x,
                                                   const unsigned short* __restrict__ wbf,
                                                   unsigned short* __restrict__ qn) {
    const int blk = blockIdx.x;
    const int win = blk >> 3;
    const int t0  = (blk & 7) << 7;
    const int b   = win >> 2;
    const int h0  = ((win >> 1) & 1) << 5;
    const int w0  = (win & 1) << 5;

    __shared__ __align__(16) unsigned short lA[256][40];  // W tile [c][k]
    __shared__ __align__(16) unsigned short lB[128][40];  // X tile [t][k]
    __shared__ float nbuf[4][128];

    const int tid  = threadIdx.x;
    const int lane = tid & 63;
    const int wv   = tid >> 6;
    const int lo   = lane & 15;
    const int hi   = lane >> 4;

    f32x4 acc[4][8];
#pragma unroll
    for (int mi = 0; mi < 4; ++mi)
#pragma unroll
        for (int ni = 0; ni < 8; ++ni) acc[mi][ni] = (f32x4){0.f, 0.f, 0.f, 0.f};

    const float* xblk = x + (size_t)b * 512 * 4096 + (size_t)(h0 + (t0 >> 5)) * 64 + w0;

    // B-stage decomposition: thread -> token-pair tp(0..63), ch-group cg(0..3)
    const int tp = tid & 63;
    const int cg = tid >> 6;
    const int tt = tp * 2;
    const int pos = ((tt >> 5) << 6) + (tt & 31);

    for (int kt = 0; kt < 16; ++kt) {
        const int k0 = kt << 5;
        // stage A: 256x32 bf16 (16B vector copies)
#pragma unroll
        for (int r = 0; r < 4; ++r) {
            int cid = r * 256 + tid;        // 0..1023
            int c   = cid >> 2;
            int n8  = cid & 3;
            *(short8*)&lA[c][n8 * 8] = *(const short8*)(wbf + c * 512 + k0 + n8 * 8);
        }
        // stage B: 128tok x 32ch; float2 loads (2 tok, 1 ch) x 8 ch -> 2 b128 writes
        {
            const float* xp = xblk + (size_t)(k0 + cg * 8) * 4096 + pos;
            short8 v0, v1;
#pragma unroll
            for (int i = 0; i < 8; ++i) {
                f32x2 d = *(const f32x2*)(xp + (size_t)i * 4096);
                v0[i] = (short)f2bf(d[0]);
                v1[i] = (short)f2bf(d[1]);
            }
            *(short8*)&lB[tt][cg * 8]     = v0;
            *(short8*)&lB[tt + 1][cg * 8] = v1;
        }
        __syncthreads();

        short8 af[4], bfr[8];
#pragma unroll
        for (int mi = 0; mi < 4; ++mi)
            af[mi] = *(const short8*)&lA[wv * 64 + mi * 16 + lo][hi * 8];
#pragma unroll
        for (int ni = 0; ni < 8; ++ni)
            bfr[ni] = *(const short8*)&lB[ni * 16 + lo][hi * 8];
#pragma unroll
        for (int mi = 0; mi < 4; ++mi)
#pragma unroll
            for (int ni = 0; ni < 8; ++ni)
                acc[mi][ni] = __builtin_amdgcn_mfma_f32_16x16x32_bf16(af[mi], bfr[ni], acc[mi][ni], 0, 0, 0);
        __syncthreads();
    }

    // ---- per-token norm over c ----
    float part[8];
#pragma unroll
    for (int ni = 0; ni < 8; ++ni) {
        float s = 0.f;
#pragma unroll
        for (int mi = 0; mi < 4; ++mi)
#pragma unroll
            for (int r = 0; r < 4; ++r) s += acc[mi][ni][r] * acc[mi][ni][r];
        s += __shfl_xor(s, 16);
        s += __shfl_xor(s, 32);
        part[ni] = s;
    }
    if (hi == 0) {
#pragma unroll
        for (int ni = 0; ni < 8; ++ni) nbuf[wv][ni * 16 + lo] = part[ni];
    }
    __syncthreads();

    char* qwin_out = (char*)(qn + (size_t)win * 1024 * 256);
#pragma unroll
    for (int ni = 0; ni < 8; ++ni) {
        const int tl = ni * 16 + lo;
        float s = nbuf[0][tl] + nbuf[1][tl] + nbuf[2][tl] + nbuf[3][tl];
        float inv = 1.f / (sqrtf(s) + 1e-6f);
        const int rq = t0 + tl;
        const int swz = (rq & 7) << 4;
#pragma unroll
        for (int mi = 0; mi < 4; ++mi) {
            int c = wv * 64 + mi * 16 + hi * 4;
            ushort4v o = {f2bf(acc[mi][ni][0] * inv), f2bf(acc[mi][ni][1] * inv),
                          f2bf(acc[mi][ni][2] * inv), f2bf(acc[mi][ni][3] * inv)};
            size_t off = ((size_t)rq * 512 + (size_t)(c * 2)) ^ (size_t)swz;
            *(ushort4v*)(qwin_out + off) = o;
        }
    }
}

// ---------------- K2: S^T = K Q^T (swapped mfma), relu, packed P, PV ----------------
// grid: 512 = 128 windows * 4 query-blocks (256 q each); bid&127 = window (XCD swizzle).
// Keys staged by linear DMA (global_load_lds) from pre-swizzled qn.
__global__ __launch_bounds__(256, 2) void k2_attn(const unsigned short* __restrict__ qn,
                                                  const float* __restrict__ v,
                                                  float* __restrict__ out) {
    const int g   = blockIdx.x;
    const int win = g & 127;
    const int qb  = g >> 7;
    const int b   = win >> 2;
    const int h0  = ((win >> 1) & 1) << 5;
    const int w0  = (win & 1) << 5;

    __shared__ __align__(16) unsigned short lK[64 * 256];   // swizzled key image, 32 KB
    __shared__ __align__(16) unsigned short lP[256][72];    // P [q][key], 36 KB, wave-private rows
    __shared__ __align__(16) unsigned short lV[16][72];     // V^T [ch][key], row15 = ones

    const int tid  = threadIdx.x;
    const int lane = tid & 63;
    const int wv   = tid >> 6;
    const int lo   = lane & 15;
    const int hi   = lane >> 4;

    const char* qwin = (const char*)(qn + (size_t)win * 1024 * 256);
    const int qw0 = qb * 256 + wv * 64;

    // hoisted Q fragments (swizzled reads)
    short8 qa[4][8];
#pragma unroll
    for (int mi = 0; mi < 4; ++mi) {
        const int rq = qw0 + mi * 16 + lo;
        const size_t swz = (size_t)((rq & 7) << 4);
#pragma unroll
        for (int kc = 0; kc < 8; ++kc)
            qa[mi][kc] = *(const short8*)(qwin + (((size_t)rq * 512 + kc * 64 + hi * 16) ^ swz));
    }

    f32x4 accout[4];
#pragma unroll
    for (int t = 0; t < 4; ++t) accout[t] = (f32x4){0.f, 0.f, 0.f, 0.f};

    const float* vbase = v + (size_t)b * 15 * 4096 + (size_t)h0 * 64 + w0;
    char* lKb = (char*)lK;
    char* lPb = (char*)&lP[0][0];
    char* lVb = (char*)&lV[0][0];

    for (int chk = 0; chk < 16; ++chk) {
        const int kbase = chk << 6;
        __syncthreads();   // prev chunk's lK/lV reads done
        // stage keys: linear 32KB DMA from swizzled qn
        {
            const char* src = qwin + (size_t)kbase * 512;
#pragma unroll
            for (int r = 0; r < 8; ++r) {
                int idx = (r * 256 + tid) * 16;
                gload_lds16(src + idx, lKb + idx);
            }
        }
        // stage V^T 16x64 (ch 15 = ones): float4 + packed b64 write
        {
            const int chn = tid & 15;
            const int kp  = tid >> 4;   // 0..15
            uint32x2 u;
            if (chn < 15) {
                int jk = kbase + kp * 4;
                const float* vp = vbase + (size_t)chn * 4096 + ((jk >> 5) * 64 + (jk & 31));
                f32x4 d = *(const f32x4*)vp;
                u[0] = pack2(d[0], d[1]);
                u[1] = pack2(d[2], d[3]);
            } else {
                u[0] = 0x3F803F80u;
                u[1] = 0x3F803F80u;
            }
            *(uint32x2*)(lVb + chn * 144 + kp * 8) = u;
        }
        __syncthreads();   // drains DMA (vmcnt) + lV writes

        // S^T: per ni (key-16-tile): D = mfma(A=kb, B=qa) -> lane: col=q(lo), rows=key(4hi+r)
#pragma unroll
        for (int ni = 0; ni < 4; ++ni) {
            f32x4 st[4];
#pragma unroll
            for (int mi = 0; mi < 4; ++mi) st[mi] = (f32x4){0.f, 0.f, 0.f, 0.f};
#pragma unroll
            for (int kc = 0; kc < 8; ++kc) {
                const int row = ni * 16 + lo;
                const int off = ((row * 512) + kc * 64 + hi * 16) ^ ((row & 7) << 4);
                short8 kb = *(const short8*)(lKb + off);
#pragma unroll
                for (int mi = 0; mi < 4; ++mi)
                    st[mi] = __builtin_amdgcn_mfma_f32_16x16x32_bf16(kb, qa[mi][kc], st[mi], 0, 0, 0);
            }
            // relu -> packed bf16 pairs -> b64 write: lP[q = wv*64+mi*16+lo][key = ni*16+4hi .. +3]
#pragma unroll
            for (int mi = 0; mi < 4; ++mi) {
                uint32x2 u;
                u[0] = pack2(fmaxf(st[mi][0], 0.f), fmaxf(st[mi][1], 0.f));
                u[1] = pack2(fmaxf(st[mi][2], 0.f), fmaxf(st[mi][3], 0.f));
                *(uint32x2*)(lPb + (wv * 64 + mi * 16 + lo) * 144 + ni * 32 + hi * 8) = u;
            }
        }

        // PV: per wave 64q, N=16 (15 v-ch + rowsum), K=64 (same-wave LDS, no barrier)
#pragma unroll
        for (int t = 0; t < 4; ++t) {
#pragma unroll
            for (int ks = 0; ks < 2; ++ks) {
                short8 pa  = *(const short8*)(lPb + (wv * 64 + t * 16 + lo) * 144 + ks * 64 + hi * 16);
                short8 vbf = *(const short8*)(lVb + lo * 144 + ks * 64 + hi * 16);
                accout[t] = __builtin_amdgcn_mfma_f32_16x16x32_bf16(pa, vbf, accout[t], 0, 0, 0);
            }
        }
    }

    // epilogue: divide by rowsum (ch 15) and store. D: lane lo = channel, (hi,r) = q.
#pragma unroll
    for (int t = 0; t < 4; ++t) {
#pragma unroll
        for (int r = 0; r < 4; ++r) {
            float rs = __shfl(accout[t][r], (lane & 48) | 15);
            if (lo < 15) {
                int q = qw0 + t * 16 + hi * 4 + r;
                out[(size_t)(b * 15 + lo) * 4096 + (size_t)(h0 + (q >> 5)) * 64 + (w0 + (q & 31))] =
                    accout[t][r] / (rs + 1e-6f);
            }
        }
    }
}

extern "C" void kernel_launch(void* const* d_in, const int* in_sizes, int n_in,
                              void* d_out, int out_size, void* d_ws, size_t ws_size,
                              hipStream_t stream) {
    const float* x = (const float*)d_in[0];
    const float* v = (const float*)d_in[1];
    const float* w = (const float*)d_in[2];
    float* out = (float*)d_out;

    unsigned short* qn  = (unsigned short*)d_ws;                         // 64 MiB (swizzled)
    unsigned short* wbf = (unsigned short*)((char*)d_ws + (size_t)128 * 1024 * 256 * 2);

    k0_cvt<<<512, 256, 0, stream>>>(w, wbf, 256 * 512);
    k1_qgemm<<<1024, 256, 0, stream>>>(x, wbf, qn);
    k2_attn<<<512, 256, 0, stream>>>(qn, v, out);
}